// Round 1
// baseline (529.527 us; speedup 1.0000x reference)
//
#include <hip/hip_runtime.h>

namespace {

constexpr int H = 8192;
constexpr int W = 8192;
constexpr int RB = 8;                    // rows per block
constexpr int TPB = 256;                 // threads per block (4 waves)
constexpr int COLS_PER_BLK = TPB * 4;    // 1024 columns per block
constexpr float EPS = 1e-12f;

// loss for one element; hmax = 3x3 window max of target (pos iff ==1.0)
__device__ __forceinline__ float elem_loss(float p, float t, float hmax) {
    const bool pos = (hmax == 1.0f);
    const float d  = fabsf(t - p);
    const float x  = pos ? (1.0f - d) : (1.0f - p + EPS);
    const float g  = 1.0f - t;
    const float g2 = g * g;
    const float f  = pos ? (d * d) : (p * p * g2 * g2);
    return -__logf(x) * f;
}

__global__ __launch_bounds__(TPB) void focal_kernel(const float* __restrict__ pred,
                                                    const float* __restrict__ targ,
                                                    double* __restrict__ acc) {
    const int r0 = blockIdx.y * RB;
    const int cb = blockIdx.x * COLS_PER_BLK;
    const int c0 = cb + (int)threadIdx.x * 4;
    const int v4 = c0 >> 2;

    const bool has_left  = (c0 > 0);
    const bool has_right = (c0 + 4 < W);

    const float4* tv = reinterpret_cast<const float4*>(targ);
    const float4* pv = reinterpret_cast<const float4*>(pred);
    const int row4 = W >> 2;

    // 3-row register window over target: A = row r-1, B = row r, C = row r+1
    float4 tA, tB;
    float lA, lB, rA, rB;
    if (r0 > 0) {
        tA = tv[(size_t)(r0 - 1) * row4 + v4];
        lA = has_left  ? targ[(size_t)(r0 - 1) * W + c0 - 1] : 0.0f;
        rA = has_right ? targ[(size_t)(r0 - 1) * W + c0 + 4] : 0.0f;
    } else {
        tA = make_float4(0.f, 0.f, 0.f, 0.f); lA = 0.f; rA = 0.f;
    }
    {
        tB = tv[(size_t)r0 * row4 + v4];
        lB = has_left  ? targ[(size_t)r0 * W + c0 - 1] : 0.0f;
        rB = has_right ? targ[(size_t)r0 * W + c0 + 4] : 0.0f;
    }

    float lsum = 0.0f;
#pragma unroll
    for (int rr = 0; rr < RB; ++rr) {
        const int r = r0 + rr;
        float4 tC; float lC, rC;
        if (r + 1 < H) {
            tC = tv[(size_t)(r + 1) * row4 + v4];
            lC = has_left  ? targ[(size_t)(r + 1) * W + c0 - 1] : 0.0f;
            rC = has_right ? targ[(size_t)(r + 1) * W + c0 + 4] : 0.0f;
        } else {
            tC = make_float4(0.f, 0.f, 0.f, 0.f); lC = 0.f; rC = 0.f;
        }

        const float4 p = pv[(size_t)r * row4 + v4];

        // vertical max across 3 rows, per column
        const float vm0 = fmaxf(tB.x, fmaxf(tA.x, tC.x));
        const float vm1 = fmaxf(tB.y, fmaxf(tA.y, tC.y));
        const float vm2 = fmaxf(tB.z, fmaxf(tA.z, tC.z));
        const float vm3 = fmaxf(tB.w, fmaxf(tA.w, tC.w));
        const float lm  = fmaxf(lB, fmaxf(lA, lC));
        const float rm  = fmaxf(rB, fmaxf(rA, rC));

        // horizontal max over 3 columns
        const float h0 = fmaxf(lm,  fmaxf(vm0, vm1));
        const float h1 = fmaxf(vm0, fmaxf(vm1, vm2));
        const float h2 = fmaxf(vm1, fmaxf(vm2, vm3));
        const float h3 = fmaxf(vm2, fmaxf(vm3, rm));

        lsum += elem_loss(p.x, tB.x, h0);
        lsum += elem_loss(p.y, tB.y, h1);
        lsum += elem_loss(p.z, tB.z, h2);
        lsum += elem_loss(p.w, tB.w, h3);

        // slide window down one row
        tA = tB; tB = tC;
        lA = lB; lB = lC;
        rA = rB; rB = rC;
    }

    // wave64 butterfly reduce
#pragma unroll
    for (int off = 32; off > 0; off >>= 1) lsum += __shfl_down(lsum, off);

    __shared__ float wsum[TPB / 64];
    const int wid = (int)threadIdx.x >> 6;
    if (((int)threadIdx.x & 63) == 0) wsum[wid] = lsum;
    __syncthreads();
    if (threadIdx.x == 0) {
        float s = 0.f;
#pragma unroll
        for (int i = 0; i < TPB / 64; ++i) s += wsum[i];
        atomicAdd(acc, (double)s);
    }
}

__global__ void finalize_kernel(const double* __restrict__ acc, float* __restrict__ out) {
    out[0] = (float)(acc[0] * (1.0 / ((double)H * (double)W)));
}

} // namespace

extern "C" void kernel_launch(void* const* d_in, const int* in_sizes, int n_in,
                              void* d_out, int out_size, void* d_ws, size_t ws_size,
                              hipStream_t stream) {
    const float* pred = (const float*)d_in[0];
    const float* targ = (const float*)d_in[1];
    float* out = (float*)d_out;
    double* acc = (double*)d_ws;

    // d_ws is poisoned 0xAA before every launch — zero the accumulator.
    hipMemsetAsync(d_ws, 0, sizeof(double), stream);

    dim3 grid(W / COLS_PER_BLK, H / RB);  // (8, 1024)
    focal_kernel<<<grid, TPB, 0, stream>>>(pred, targ, acc);
    finalize_kernel<<<1, 1, 0, stream>>>(acc, out);
}